// Round 6
// baseline (407.863 us; speedup 1.0000x reference)
//
#include <hip/hip_runtime.h>
#include <hip/hip_fp16.h>
#include <math.h>

#define H 256

typedef _Float16 f16x8 __attribute__((ext_vector_type(8)));
typedef _Float16 f16x4 __attribute__((ext_vector_type(4)));
typedef float    f32x4 __attribute__((ext_vector_type(4)));
typedef _Float16 h2_t  __attribute__((ext_vector_type(2)));
union U16x8 { uint4 u; h2_t h[4]; };

// ---- workspace layout (float offsets) ----
#define WS_WF_T  0u          // 98304 f32-equiv = 196608 halves (term Whh, MFMA A-frag layout)
#define WS_WF_C  98304u
#define WS_WF_A  196608u
#define WS_W16T  294912u     // flat fp16 [768][256] of term Wih
#define WS_W16C  393216u
#define WS_W16A  491520u
#define WS_W16Q  589824u     // qry Wih fp16 flat
#define WS_PT    688128u     // 66560 f32: posd_W^T [260][256]
#define WS_GI_T  754688u     // 20*64*768 fp16 (uses half the f32-sized slot)
#define WS_GI_C  1737728u    // 50*24*768 fp16
#define WS_GI_A  2659328u
#define WS_ENC   3580928u    // 64*256 f32
#define WS_HC    3597312u    // 24*256
#define WS_HA    3603456u    // 24*256

__device__ __forceinline__ float sigmoidf_(float x){ return 1.f/(1.f+expf(-x)); }

// ---------------- K0: fused weight prep ----------------
// A) blocks [0,2304): Whh{t,c,a} -> fp16 MFMA A-frag layout.
//    elem i in [0,196608): f=i>>9, lane=(i>>3)&63, e=i&7;
//    row=(f>>3)*16+(lane&15), k=(f&7)*32+((lane>>4)&3)*8+e
// B) blocks [2304,5376): {tWih,cWih,aWih,qWih} f32 -> fp16 flat
// C) blocks [5376,5636): posd_W [256][260] -> PT [260][256] f32
__global__ __launch_bounds__(256) void k_prep2(
    const float* __restrict__ tWhh, const float* __restrict__ cWhh, const float* __restrict__ aWhh,
    const float* __restrict__ tWih, const float* __restrict__ cWih, const float* __restrict__ aWih,
    const float* __restrict__ qWih, const float* __restrict__ pdW,
    _Float16* __restrict__ WFt, _Float16* __restrict__ WFc, _Float16* __restrict__ WFa,
    _Float16* __restrict__ W16t, _Float16* __restrict__ W16c, _Float16* __restrict__ W16a,
    _Float16* __restrict__ W16q, float* __restrict__ PT)
{
    const int b = blockIdx.x, tid = threadIdx.x;
    if (b < 2304) {
        int i = b * 256 + tid;               // 0 .. 589823
        int m = i / 196608, r = i % 196608;
        const float* in = (m == 0) ? tWhh : (m == 1) ? cWhh : aWhh;
        _Float16*   out = (m == 0) ? WFt  : (m == 1) ? WFc  : WFa;
        int f = r >> 9, lane = (r >> 3) & 63, e = r & 7;
        int row = (f >> 3) * 16 + (lane & 15);
        int k   = (f & 7) * 32 + ((lane >> 4) & 3) * 8 + e;
        out[r] = (_Float16)in[row * 256 + k];
        return;
    }
    if (b < 5376) {
        int i = (b - 2304) * 256 + tid;      // 0 .. 786431
        int m = i / 196608, r = i % 196608;
        const float* in = (m == 0) ? tWih : (m == 1) ? cWih : (m == 2) ? aWih : qWih;
        _Float16*   out = (m == 0) ? W16t : (m == 1) ? W16c : (m == 2) ? W16a : W16q;
        out[r] = (_Float16)in[r];
        return;
    }
    {
        int i = (b - 5376) * 256 + tid;      // 0 .. 66559
        int k = i >> 8, j = i & 255;
        PT[k * 256 + j] = pdW[j * 260 + k];
    }
}

// ---------------- K1: gi GEMM via MFMA fp16, fp16 output ----------------
__global__ __launch_bounds__(256) void k_gi2(
    const int* __restrict__ qtok, const int* __restrict__ ptok, const int* __restrict__ ntok,
    const float* __restrict__ temb, const float* __restrict__ demb,
    const _Float16* __restrict__ W16t, const _Float16* __restrict__ W16c, const _Float16* __restrict__ W16a,
    const float* __restrict__ tbih, const float* __restrict__ cbih, const float* __restrict__ abih,
    _Float16* __restrict__ git, _Float16* __restrict__ gic, _Float16* __restrict__ gia)
{
    __shared__ __align__(16) _Float16 At[64 * 264];
    __shared__ int tok[64];

    const int bid = blockIdx.x, tid = threadIdx.x;
    const float *emb, *bih; const _Float16* W16; _Float16* out; int nrows, seg, mt, nt;
    if (bid < 240)      { seg = 0; int b = bid;       mt = b / 12; nt = b % 12; emb = temb; W16 = W16t; bih = tbih; out = git; nrows = 1280; }
    else if (bid < 468) { seg = 1; int b = bid - 240; mt = b / 12; nt = b % 12; emb = demb; W16 = W16c; bih = cbih; out = gic; nrows = 1200; }
    else                { seg = 2; int b = bid - 468; mt = b / 12; nt = b % 12; emb = demb; W16 = W16a; bih = abih; out = gia; nrows = 1200; }
    const int rowbase = mt * 64, jb = nt * 64;

    if (tid < 64) {
        int rg = rowbase + tid;
        int token = 0;
        if (rg < nrows) {
            if (seg == 0) { int t = mt, q = tid; token = qtok[q * 20 + t]; }
            else          { int t = rg / 24, d = rg % 24; token = (d < 12) ? ptok[d * 50 + t] : ntok[(d - 12) * 50 + t]; }
        }
        tok[tid] = token;
    }
    __syncthreads();

#pragma unroll
    for (int i = 0; i < 16; i++) {
        int idx = i * 256 + tid;
        int r = idx >> 6, c4 = idx & 63;
        float4 v = *(const float4*)(emb + (size_t)tok[r] * H + c4 * 4);
        f16x4 hv = { (_Float16)v.x, (_Float16)v.y, (_Float16)v.z, (_Float16)v.w };
        *(f16x4*)(At + r * 264 + c4 * 4) = hv;
    }
    __syncthreads();

    const int wave = tid >> 6, lane = tid & 63;
    const int rt = wave;
    const int kg = (lane >> 4) & 3;

    f16x8 af[8];
    const _Float16* abase = At + (rt * 16 + (lane & 15)) * 264 + kg * 8;
#pragma unroll
    for (int kt = 0; kt < 8; kt++) af[kt] = *(const f16x8*)(abase + kt * 32);

#pragma unroll
    for (int ct = 0; ct < 4; ct++) {
        const int col = jb + ct * 16 + (lane & 15);
        const _Float16* wrow = W16 + (size_t)col * H + kg * 8;
        f32x4 acc = {0.f, 0.f, 0.f, 0.f};
#pragma unroll
        for (int kt = 0; kt < 8; kt++) {
            f16x8 bf = *(const f16x8*)(wrow + kt * 32);
            acc = __builtin_amdgcn_mfma_f32_16x16x32_f16(af[kt], bf, acc, 0, 0, 0);
        }
        float bias = bih[col];
#pragma unroll
        for (int e = 0; e < 4; e++) {
            int row_g = rowbase + rt * 16 + kg * 4 + e;
            if (row_g < nrows)
                out[(size_t)row_g * 768 + col] = (_Float16)(acc[e] + bias);
        }
    }
}

// ---------------- K2: recurrent scans, 16 chains/block, MFMA N=16, forced-resident frags ----
// 8 blocks x 768 thr (12 waves). Wave w owns gate-rows w*64..w*64+63 as 32 A-frags (128 VGPR).
// Per step: B-frag = h of 16 chains (all lanes useful), 32 mfma/wave, D -> gh via ds_write_b128,
// then 16x256 GRU update. asm "+v" inside the loop pins the fragments in registers.
__global__ __launch_bounds__(768, 3) void k_recur6(
    const _Float16* __restrict__ WFt, const _Float16* __restrict__ WFc, const _Float16* __restrict__ WFa,
    const float* __restrict__ tbhh, const float* __restrict__ cbhh, const float* __restrict__ abhh,
    const _Float16* __restrict__ gi_t, const _Float16* __restrict__ gi_c, const _Float16* __restrict__ gi_a,
    float* __restrict__ enc, float* __restrict__ hc, float* __restrict__ ha)
{
    __shared__ __align__(16) _Float16 hh[16][264];   // h fp16 (B operand), padded
    __shared__ __align__(16) float    hf[16][260];   // h fp32 state
    __shared__ __align__(16) float    gh[16][780];   // Whh@h per chain x gate-row
    __shared__ float bg[768];                        // bhh staged

    const int b = blockIdx.x, tid = threadIdx.x;
    const _Float16* WF; const float* bhh; const _Float16* gi; float* outp;
    int T, nch_g, ch0, ncl;
    if (b < 4)      { WF = WFt; bhh = tbhh; gi = gi_t; T = 20; nch_g = 64; ch0 = b * 16;       ncl = 16; outp = enc; }
    else if (b < 6) { WF = WFc; bhh = cbhh; gi = gi_c; T = 50; nch_g = 24; ch0 = (b - 4) * 12; ncl = 12; outp = hc; }
    else            { WF = WFa; bhh = abhh; gi = gi_a; T = 50; nch_g = 24; ch0 = (b - 6) * 12; ncl = 12; outp = ha; }

    const int wave = tid >> 6, lane = tid & 63;
    const int chn = lane & 15;          // B/D column = chain
    const int kq  = lane >> 4;          // 0..3

    // 32 resident A-fragments (frag i = rowtile*8 + ktile, global frag = wave*32+i)
    const f16x8* __restrict__ WFp = (const f16x8*)WF;
    f16x8 wf[32];
#pragma unroll
    for (int i = 0; i < 32; i++) wf[i] = WFp[(size_t)(wave * 32 + i) * 64 + lane];

    bg[tid] = bhh[tid];
    for (int i = tid; i < 16 * 264; i += 768) ((_Float16*)hh)[i] = (_Float16)0.f;
    for (int i = tid; i < 16 * 260; i += 768) ((float*)hf)[i] = 0.f;
    __syncthreads();

    for (int t = 0; t < T; t++) {
#pragma unroll
        for (int i = 0; i < 32; i++) asm volatile("" : "+v"(wf[i]));   // pin in VGPRs

        f32x4 acc0 = {0.f,0.f,0.f,0.f}, acc1 = {0.f,0.f,0.f,0.f};
        f32x4 acc2 = {0.f,0.f,0.f,0.f}, acc3 = {0.f,0.f,0.f,0.f};
#pragma unroll
        for (int kt = 0; kt < 8; kt++) {
            f16x8 bv = *(const f16x8*)&hh[chn][kt * 32 + kq * 8];
            acc0 = __builtin_amdgcn_mfma_f32_16x16x32_f16(wf[kt],      bv, acc0, 0, 0, 0);
            acc1 = __builtin_amdgcn_mfma_f32_16x16x32_f16(wf[8 + kt],  bv, acc1, 0, 0, 0);
            acc2 = __builtin_amdgcn_mfma_f32_16x16x32_f16(wf[16 + kt], bv, acc2, 0, 0, 0);
            acc3 = __builtin_amdgcn_mfma_f32_16x16x32_f16(wf[24 + kt], bv, acc3, 0, 0, 0);
        }
        {
            const int r0 = wave * 64 + kq * 4;
            *(f32x4*)&gh[chn][r0     ] = acc0;
            *(f32x4*)&gh[chn][r0 + 16] = acc1;
            *(f32x4*)&gh[chn][r0 + 32] = acc2;
            *(f32x4*)&gh[chn][r0 + 48] = acc3;
        }
        __syncthreads();

        for (int p = 0; p < 6; p++) {
            int idx = p * 768 + tid;
            int c = idx >> 8, j = idx & 255;
            if (c < ncl) {
                const _Float16* __restrict__ grow = gi + (size_t)(t * nch_g + ch0 + c) * 768;
                float gr = (float)grow[j], gz = (float)grow[j + 256], gn = (float)grow[j + 512];
                float r = sigmoidf_(gr + bg[j]       + gh[c][j]);
                float z = sigmoidf_(gz + bg[j + 256] + gh[c][j + 256]);
                float n = tanhf(gn + r * (bg[j + 512] + gh[c][j + 512]));
                float hn = (1.f - z) * n + z * hf[c][j];
                hf[c][j] = hn;
                hh[c][j] = (_Float16)hn;
            }
        }
        __syncthreads();
    }

    for (int p = 0; p < 6; p++) {
        int idx = p * 768 + tid;
        int c = idx >> 8, j = idx & 255;
        if (c < ncl) outp[(size_t)(ch0 + c) * H + j] = hf[c][j];
    }
}

// ---------------- K3: attention + folded position-dense + final GRU, 1 block/query ----
__global__ __launch_bounds__(256) void k_final2(
    const float* __restrict__ enc, const float* __restrict__ ha, const float* __restrict__ hc,
    const float* __restrict__ ptab, const float* __restrict__ PT, const float* __restrict__ pdb,
    const _Float16* __restrict__ qW16, const float* __restrict__ qbih, const float* __restrict__ qbhh,
    float* __restrict__ out)
{
    __shared__ __align__(16) float ql[H];
    __shared__ __align__(16) float csl[H];
    __shared__ float csp[4];
    __shared__ float wts[24];
    __shared__ __align__(16) _Float16 q2h[H];

    const int q = blockIdx.x, j = threadIdx.x;
    ql[j] = enc[q * H + j];
    __syncthreads();

    if (j < 192) {
        int dd = j >> 3, l8 = j & 7;
        float s = 0.f;
        for (int k = l8 * 32; k < l8 * 32 + 32; k++) s += ha[dd * H + k] * ql[k];
        s += __shfl_xor(s, 1); s += __shfl_xor(s, 2); s += __shfl_xor(s, 4);
        if (l8 == 0) wts[dd] = s;
    }
    __syncthreads();
    if (j < 2) {
        int base = j * 12;
        float m = wts[base];
        for (int d = 1; d < 12; d++) m = fmaxf(m, wts[base + d]);
        float sum = 0.f;
        for (int d = 0; d < 12; d++) { float e = expf(wts[base + d] - m); wts[base + d] = e; sum += e; }
        float inv = 1.f / sum;
        for (int d = 0; d < 12; d++) wts[base + d] *= inv;
    }
    __syncthreads();

    {
        float cs = 0.f;
#pragma unroll 4
        for (int d = 0; d < 24; d++) cs += wts[d] * hc[d * H + j];
        csl[j] = cs;
    }
    if (j < 4) {
        float cp = 0.f;
        for (int d = 0; d < 24; d++) cp += wts[d] * ptab[(d % 12) * 4 + j];
        csp[j] = cp;
    }
    __syncthreads();

    float att = 2.f * pdb[j];
#pragma unroll 4
    for (int k = 0; k < 256; k++) att += csl[k] * PT[(size_t)k * 256 + j];
#pragma unroll
    for (int k = 0; k < 4; k++)   att += csp[k] * PT[(size_t)(256 + k) * 256 + j];

    float q2 = ql[j] + att;
    q2h[j] = (_Float16)q2;
    __syncthreads();

    const uint4* q4 = (const uint4*)q2h;
    const uint4* w0 = (const uint4*)(qW16 + (size_t)(j      ) * H);
    const uint4* w1 = (const uint4*)(qW16 + (size_t)(j + 256) * H);
    const uint4* w2 = (const uint4*)(qW16 + (size_t)(j + 512) * H);
    float ar = 0.f, az = 0.f, an = 0.f;
#pragma unroll 8
    for (int k8 = 0; k8 < 32; k8++) {
        U16x8 hv; hv.u = q4[k8];
        U16x8 a; a.u = w0[k8];
        U16x8 bb; bb.u = w1[k8];
        U16x8 c; c.u = w2[k8];
#pragma unroll
        for (int p = 0; p < 4; p++) {
            ar = __builtin_amdgcn_fdot2(a.h[p],  hv.h[p], ar, false);
            az = __builtin_amdgcn_fdot2(bb.h[p], hv.h[p], az, false);
            an = __builtin_amdgcn_fdot2(c.h[p],  hv.h[p], an, false);
        }
    }
    float r = sigmoidf_(ar + qbih[j]       + qbhh[j]);
    float z = sigmoidf_(az + qbih[j + 256] + qbhh[j + 256]);
    float n = tanhf(an + qbih[j + 512] + r * qbhh[j + 512]);
    out[q * H + j] = (1.f - z) * n;
}

extern "C" void kernel_launch(void* const* d_in, const int* in_sizes, int n_in,
                              void* d_out, int out_size, void* d_ws, size_t ws_size,
                              hipStream_t stream)
{
    const int*   qtok = (const int*)d_in[0];
    const int*   ptok = (const int*)d_in[1];
    const int*   ntok = (const int*)d_in[2];
    const float* temb = (const float*)d_in[3];
    const float* tWih = (const float*)d_in[4];
    const float* tWhh = (const float*)d_in[5];
    const float* tbih = (const float*)d_in[6];
    const float* tbhh = (const float*)d_in[7];
    const float* demb = (const float*)d_in[8];
    const float* cWih = (const float*)d_in[9];
    const float* cWhh = (const float*)d_in[10];
    const float* cbih = (const float*)d_in[11];
    const float* cbhh = (const float*)d_in[12];
    const float* aWih = (const float*)d_in[13];
    const float* aWhh = (const float*)d_in[14];
    const float* abih = (const float*)d_in[15];
    const float* abhh = (const float*)d_in[16];
    const float* ptab = (const float*)d_in[17];
    const float* pdW  = (const float*)d_in[18];
    const float* pdb  = (const float*)d_in[19];
    const float* qWih = (const float*)d_in[20];
    const float* qbih = (const float*)d_in[22];
    const float* qbhh = (const float*)d_in[23];

    float* ws = (float*)d_ws;
    _Float16* WFt  = (_Float16*)(ws + WS_WF_T);
    _Float16* WFc  = (_Float16*)(ws + WS_WF_C);
    _Float16* WFa  = (_Float16*)(ws + WS_WF_A);
    _Float16* W16t = (_Float16*)(ws + WS_W16T);
    _Float16* W16c = (_Float16*)(ws + WS_W16C);
    _Float16* W16a = (_Float16*)(ws + WS_W16A);
    _Float16* W16q = (_Float16*)(ws + WS_W16Q);
    float* PT  = ws + WS_PT;
    _Float16* GIt = (_Float16*)(ws + WS_GI_T);
    _Float16* GIc = (_Float16*)(ws + WS_GI_C);
    _Float16* GIa = (_Float16*)(ws + WS_GI_A);
    float* ENC = ws + WS_ENC;
    float* HC  = ws + WS_HC;
    float* HA  = ws + WS_HA;

    k_prep2<<<5636, 256, 0, stream>>>(tWhh, cWhh, aWhh, tWih, cWih, aWih, qWih, pdW,
                                      WFt, WFc, WFa, W16t, W16c, W16a, W16q, PT);

    k_gi2<<<696, 256, 0, stream>>>(qtok, ptok, ntok, temb, demb,
                                   W16t, W16c, W16a, tbih, cbih, abih,
                                   GIt, GIc, GIa);

    k_recur6<<<8, 768, 0, stream>>>(WFt, WFc, WFa, tbhh, cbhh, abhh,
                                    GIt, GIc, GIa, ENC, HC, HA);

    k_final2<<<64, 256, 0, stream>>>(ENC, HA, HC, ptab, PT, pdb,
                                     W16q, qbih, qbhh, (float*)d_out);
}